// Round 7
// baseline (273.267 us; speedup 1.0000x reference)
//
#include <hip/hip_runtime.h>
#include <float.h>

#define N_PART 262144
#define GRID_DIM 256
#define NUM_CELLS (GRID_DIM * GRID_DIM)
#define KP 32                          // padded slots per cell (= reference K)
#define MAXNB 64

// ---------------- ws layout (all 256B-aligned) ----------------
// counts : NUM_CELLS+1 ints   (zeroed in D1; [NUM_CELLS] stays 0 = clip row)
// bMinX/Y/H : 1024 floats each (per-block reduce partials)
// lin    : N ints             (cell of each particle)
// tableA : (NUM_CELLS+1)*KP ints   (raw ids, arrival order)
// Qpad   : (NUM_CELLS+1)*KP + 64 float4  ({x, y, id-bits, S}, id-sorted)
//
// Sync-point economics (r3/r5 lesson): a grid.sync() costs ~ a dispatch
// boundary; cooperative fusion saves nothing. FOUR ordinary dispatches,
// each full-occupancy, no scan/scatter/sort passes.

__global__ __launch_bounds__(256) void prep_kernel(
        const float2* __restrict__ pos2, const float* __restrict__ sup,
        int* __restrict__ counts,
        float* __restrict__ bMinX, float* __restrict__ bMinY,
        float* __restrict__ bMaxH) {
    __shared__ unsigned s_minx, s_miny, s_maxh;
    int t = threadIdx.x, b = blockIdx.x;
    int tid = b * 256 + t;
    if (tid <= NUM_CELLS) counts[tid] = 0;
    if (t == 0) { s_minx = 0x7f7fffffu; s_miny = 0x7f7fffffu; s_maxh = 0u; }
    __syncthreads();
    float2 p = pos2[tid];
    float  h = sup[tid];
    // non-negative floats: uint compare == float compare
    atomicMin(&s_minx, __float_as_uint(p.x));
    atomicMin(&s_miny, __float_as_uint(p.y));
    atomicMax(&s_maxh, __float_as_uint(h));
    __syncthreads();
    if (t == 0) {
        bMinX[b] = __uint_as_float(s_minx);
        bMinY[b] = __uint_as_float(s_miny);
        bMaxH[b] = __uint_as_float(s_maxh);
    }
}

__global__ __launch_bounds__(256) void bin_kernel(
        const float2* __restrict__ pos2,
        const float* __restrict__ bMinX, const float* __restrict__ bMinY,
        const float* __restrict__ bMaxH,
        int* __restrict__ counts, int* __restrict__ tableA,
        int* __restrict__ lin) {
    __shared__ unsigned s_minx, s_miny, s_maxh;
    int t = threadIdx.x;
    int tid = blockIdx.x * 256 + t;
    // redundant per-block combine of 1024 partials: min/max exact and
    // order-independent -> identical result in every block
    if (t == 0) { s_minx = 0x7f7fffffu; s_miny = 0x7f7fffffu; s_maxh = 0u; }
    __syncthreads();
    {
        float mx = FLT_MAX, my = FLT_MAX, mh = 0.0f;
        for (int k = t; k < 1024; k += 256) {
            mx = fminf(mx, bMinX[k]);
            my = fminf(my, bMinY[k]);
            mh = fmaxf(mh, bMaxH[k]);
        }
        atomicMin(&s_minx, __float_as_uint(mx));
        atomicMin(&s_miny, __float_as_uint(my));
        atomicMax(&s_maxh, __float_as_uint(mh));
    }
    __syncthreads();
    float hmax  = __uint_as_float(s_maxh);
    float qminx = __uint_as_float(s_minx) - hmax;
    float qminy = __uint_as_float(s_miny) - hmax;
    float2 p = pos2[tid];
    int cx = (int)ceilf((p.x - qminx) / hmax);
    int cy = (int)ceilf((p.y - qminy) / hmax);
    cx = min(max(cx, 0), GRID_DIM - 1);
    cy = min(max(cy, 0), GRID_DIM - 1);
    int c = cx + GRID_DIM * cy;
    lin[tid] = c;
    int slot = atomicAdd(&counts[c], 1);
    if (slot < KP) tableA[(c << 5) + slot] = tid;   // Poisson(4): never >32
}

// per particle: rank = #(smaller ids in my cell row) -> write the packed
// record at its FINAL id-sorted position (stable argsort semantics).
// Also precompute S = exact f32 threshold:  s2 <= S  <=>  RN(sqrt(s2)) <= h
// mid = (h + nextafterf(h))/2; mid^2 exact in double (50 bits), never a
// 24-bit f32 -> no ties; S = largest f32 <= mid^2.
__global__ __launch_bounds__(256) void rank_kernel(
        const float2* __restrict__ pos2, const float* __restrict__ sup,
        const int* __restrict__ counts, const int* __restrict__ tableA,
        const int* __restrict__ lin, float4* __restrict__ Qpad) {
    int tid = blockIdx.x * 256 + threadIdx.x;
    int c   = lin[tid];
    int cnt = min(counts[c], KP);
    const int* row = tableA + (c << 5);
    int rank = 0;
    for (int k = 0; k < cnt; k++) rank += (row[k] < tid);
    float2 p = pos2[tid];               // bitwise copy: query numerics identical
    float  h = sup[tid];
    float  hn  = __int_as_float(__float_as_int(h) + 1);     // nextafter(h,inf)
    double mid = 0.5 * ((double)h + (double)hn);
    double t2  = mid * mid;                                  // exact
    float  S   = (float)t2;                                  // RN
    S = ((double)S > t2) ? __int_as_float(__float_as_int(S) - 1) : S;
    Qpad[(c << 5) + rank] = make_float4(p.x, p.y, __int_as_float(tid), S);
}

// One wave per CELL, candidates register-cached (T<=64 fast path). Round-6
// lesson: the per-particle loop was a serial chain {readlane -> s2 ->
// ballot -> LDS write -> LDS READ -> stores} with the ~120cy LDS
// turnaround exposed every iteration (VALUBusy 29%, latency-bound). This
// version software-pipelines groups of 4 particles: phase A does compute +
// compaction LDS writes for all 4 (independent chains overlap), phase B
// does the LDS reads + batched global stores. All register arrays indexed
// by unrolled literals (no scratch). Semantics identical to the passed r6
// kernel: same candidate order, masked-ballot compaction, S-comparator.
__global__ __launch_bounds__(256) void query_kernel(
        const int* __restrict__ counts, const float4* __restrict__ Qpad,
        float* __restrict__ outN, float* __restrict__ outC,
        float* __restrict__ outR) {
#pragma clang fp contract(off)
    __shared__ int   s_id[4][4][MAXNB];   // [waveslot][u][lane]
    __shared__ float s_s2[4][4][MAXNB];

    int t    = threadIdx.x;
    int lane = t & 63;
    int wsl  = t >> 6;
    int bid  = blockIdx.x;
    int swz  = (bid & 7) * (int)(gridDim.x >> 3) + (bid >> 3);  // bijective XCD
    int cell = __builtin_amdgcn_readfirstlane(swz * 4 + wsl);

    const int offs[9] = {-257, -1, 255, -256, 0, 256, -255, 1, 257};
    int cum[10], delta[9];
    cum[0] = 0;
#pragma unroll
    for (int o = 0; o < 9; o++) {
        int cl = min(max(cell + offs[o], 0), NUM_CELLS);  // clip, dups at edges
        int cc = min(__builtin_amdgcn_readfirstlane(counts[cl]), KP);
        delta[o]   = (cl << 5) - cum[o];                  // idx = ll + delta[o]
        cum[o + 1] = cum[o] + cc;
    }
    int T   = cum[9];
    int cnt = cum[5] - cum[4];          // center-cell count (= my particles)
    if (cnt == 0) return;               // no LDS/barrier deps: safe early-out

    if (T <= 64) {
        // ---- fast path: one candidate per lane, cached in registers ----
        int dsel = delta[0];
#pragma unroll
        for (int m = 1; m < 9; m++)
            dsel = (lane >= cum[m]) ? delta[m] : dsel;
        float4 q = Qpad[lane + dsel];   // rows beyond seg count: garbage, but
                                        //  those lanes are >= some cum -> in a
                                        //  later seg or masked by maskT below
        unsigned long long maskT = (T >= 64) ? ~0ull : ((1ull << T) - 1ull);

        for (int c0 = 0; c0 < cnt; c0 += 4) {
            int   ibv[4], totv[4];
            float Sv[4];
            // ---- phase A: compute + compaction writes for 4 particles ----
#pragma unroll
            for (int u = 0; u < 4; u++) {
                int s = c0 + u;
                bool act = s < cnt;
                int src = cum[4] + (act ? s : 0);      // wave-uniform lane idx
                float px = __int_as_float(__builtin_amdgcn_readlane(__float_as_int(q.x), src));
                float py = __int_as_float(__builtin_amdgcn_readlane(__float_as_int(q.y), src));
                ibv[u]   = __builtin_amdgcn_readlane(__float_as_int(q.z), src);
                Sv[u]    = __int_as_float(__builtin_amdgcn_readlane(__float_as_int(q.w), src));
                float dx = q.x - px;
                float dy = q.y - py;
                float s2 = dx * dx + dy * dy;          // contract(off): XLA
                bool keep = (s2 <= Sv[u]) && (lane < T);
                unsigned long long bal = __ballot(s2 <= Sv[u]) & maskT;
                int rank = __builtin_amdgcn_mbcnt_hi(
                    (unsigned)(bal >> 32),
                    __builtin_amdgcn_mbcnt_lo((unsigned)bal, 0));
                if (act && keep) {                     // T<=64 -> rank < 64
                    s_id[wsl][u][rank] = __float_as_int(q.z);
                    s_s2[wsl][u][rank] = s2;
                }
                totv[u] = (int)__popcll(bal);
            }
            // ---- phase B: LDS reads + batched stores (wave-private LDS,
            //      same-wave DS ops ordered: no barrier) ----
#pragma unroll
            for (int u = 0; u < 4; u++) {
                int s = c0 + u;
                if (s < cnt) {
                    int   jj = s_id[wsl][u][lane];     // stale beyond totv[u]
                    float ss = s_s2[wsl][u][lane];     //  -> discarded below
                    bool inb = lane < totv[u];
                    float rh = __builtin_amdgcn_rsqf(Sv[u]);  // ~1/h, 1ulp
                    float vN = inb ? (float)jj : -1.0f;
                    float vR = inb ? __builtin_amdgcn_sqrtf(ss) * rh : 0.0f;
                    size_t base = (size_t)ibv[u] * MAXNB;     // 256B full row
                    outN[base + lane] = vN;
                    outR[base + lane] = vR;
                    if (lane == 0) outC[ibv[u]] = (float)totv[u];
                }
            }
        }
    } else {
        // ---- rare path (P(T>64) ~ 1e-5 per cell): batched, re-loads ----
        for (int s = 0; s < cnt; s++) {
            float4 me = Qpad[(cell << 5) + s];
            int   ib = __builtin_amdgcn_readfirstlane(__float_as_int(me.z));
            float px = __int_as_float(__builtin_amdgcn_readfirstlane(__float_as_int(me.x)));
            float py = __int_as_float(__builtin_amdgcn_readfirstlane(__float_as_int(me.y)));
            float S  = __int_as_float(__builtin_amdgcn_readfirstlane(__float_as_int(me.w)));
            int total = 0;
            for (int b0 = 0; b0 < T; b0 += 64) {
                int ll = b0 + lane;
                int dsel = delta[0];
#pragma unroll
                for (int m = 1; m < 9; m++)
                    dsel = (ll >= cum[m]) ? delta[m] : dsel;
                float4 q = Qpad[ll + dsel];
                float dx = q.x - px;
                float dy = q.y - py;
                float s2 = dx * dx + dy * dy;
                int rem = T - b0;
                unsigned long long maskT =
                    (rem >= 64) ? ~0ull : ((1ull << rem) - 1ull);
                unsigned long long bal = __ballot(s2 <= S) & maskT;
                int rank = __builtin_amdgcn_mbcnt_hi(
                    (unsigned)(bal >> 32),
                    __builtin_amdgcn_mbcnt_lo((unsigned)bal, 0));
                int w = total + rank;
                if ((s2 <= S) && (ll < T) && (w < MAXNB)) {
                    s_id[wsl][0][w] = __float_as_int(q.z);
                    s_s2[wsl][0][w] = s2;
                }
                total += (int)__popcll(bal);
            }
            int stored = min(total, MAXNB);
            int   jj = s_id[wsl][0][lane];
            float ss = s_s2[wsl][0][lane];
            bool inb = lane < stored;
            float rh = __builtin_amdgcn_rsqf(S);
            float vN = inb ? (float)jj : -1.0f;
            float vR = inb ? __builtin_amdgcn_sqrtf(ss) * rh : 0.0f;
            size_t base = (size_t)ib * MAXNB;
            outN[base + lane] = vN;
            outR[base + lane] = vR;
            if (lane == 0) outC[ib] = (float)total;
        }
    }
}

extern "C" void kernel_launch(void* const* d_in, const int* in_sizes, int n_in,
                              void* d_out, int out_size, void* d_ws, size_t ws_size,
                              hipStream_t stream) {
    const float2* pos2 = (const float2*)d_in[0];
    const float*  sup  = (const float*)d_in[1];

    char* p = (char*)d_ws;
    auto alloc = [&](size_t bytes) {
        char* q = p;
        p += (bytes + 255) & ~(size_t)255;
        return q;
    };
    int*    counts = (int*)alloc((size_t)(NUM_CELLS + 1) * 4);
    float*  bMinX  = (float*)alloc(1024 * 4);
    float*  bMinY  = (float*)alloc(1024 * 4);
    float*  bMaxH  = (float*)alloc(1024 * 4);
    int*    lin    = (int*)alloc((size_t)N_PART * 4);
    int*    tableA = (int*)alloc((size_t)(NUM_CELLS + 1) * KP * 4);
    float4* Qpad   = (float4*)alloc(((size_t)(NUM_CELLS + 1) * KP + 64) * 16);

    float* out  = (float*)d_out;
    float* outN = out;                              // N*64 neighbor ids (as f32)
    float* outC = out + (size_t)N_PART * MAXNB;     // N counts
    float* outR = outC + N_PART;                    // N*64 radial

    prep_kernel<<<N_PART / 256, 256, 0, stream>>>(pos2, sup, counts,
                                                  bMinX, bMinY, bMaxH);
    bin_kernel<<<N_PART / 256, 256, 0, stream>>>(pos2, bMinX, bMinY, bMaxH,
                                                 counts, tableA, lin);
    rank_kernel<<<N_PART / 256, 256, 0, stream>>>(pos2, sup, counts, tableA,
                                                  lin, Qpad);
    // one wave per cell: NUM_CELLS waves, 4 cells per 256-thread block
    query_kernel<<<NUM_CELLS / 4, 256, 0, stream>>>(counts, Qpad,
                                                    outN, outC, outR);
}